// Round 5
// baseline (823.019 us; speedup 1.0000x reference)
//
#include <hip/hip_runtime.h>
#include <math.h>

#define NNT 48
#define LL 32
#define BB 32
#define N2 2304            // 48*48
#define KSTEPS 72          // 2304/32
#define EPSV 1e-30f
#define ROWE (N2 + 8)      // padded LDS row (elements)

typedef __attribute__((ext_vector_type(8))) short bf16x8;
typedef __attribute__((ext_vector_type(4))) float f32x4;

__device__ __forceinline__ int ch_idx(int b, int i, int j, int n) {
    return (((b*LL + i)*(LL+1) + j)*NNT + n);
}

__device__ __forceinline__ unsigned short f2bf(float x) {
    unsigned u = __float_as_uint(x);
    u = (u + 0x7fffu + ((u >> 16) & 1u)) >> 16;   // RNE
    return (unsigned short)u;
}

// Contraction index e = c*48 + b'  (lane-contiguous on the E side).
// W[a][e] = binary[a][b'][c] = binary[a*N2 + (e%48)*48 + e/48].
// Packed into MFMA B-fragment order (bf16):
// idx = ((nt*KSTEPS+ks)*64 + l)*8 + j ; e = ks*32 + (l>>4)*8 + j ; n = nt*16 + (l&15)
__global__ void wpack_kernel(const float* __restrict__ binary, unsigned short* __restrict__ Wp) {
    int idx = blockIdx.x*256 + threadIdx.x;
    if (idx >= 3*KSTEPS*64*8) return;
    int j  = idx & 7;
    int l  = (idx >> 3) & 63;
    int ks = (idx >> 9) % KSTEPS;
    int nt = idx / (KSTEPS*512);
    int e = ks*32 + ((l >> 4) << 3) + j;
    int n = nt*16 + (l & 15);
    int bp = e % 48, c = e / 48;
    float v = fmaxf(binary[n*N2 + bp*48 + c], EPSV);
    Wp[idx] = f2bf(v);
}

// One persistent block per batch element b. 16 waves, all 31 levels serially,
// __syncthreads() between phases (block-private chart slice -> no grid sync).
// Per level: IPB = next_pow2(pos) (<=16) instances per GEMM pass, WPI = 16/IPB
// waves per instance. Merged E-build: online running max with rescale-on-growth,
// eu=exp(u-alpha)<=1, ev=exp(v+alpha-m_run)<=1 (args <=0 -> overflow-free);
// per-wave partials rescaled to the instance max M at pack time.
__global__ __launch_bounds__(1024) void inside_kernel(const unsigned short* __restrict__ Wp,
                                                      const int* __restrict__ tokens,
                                                      const float* __restrict__ lexical,
                                                      float* __restrict__ chart,
                                                      float* __restrict__ out, int T) {
    const int b = blockIdx.x;
    const int tid = threadIdx.x, lane = tid & 63, w = tid >> 6;

    __shared__ __align__(16) unsigned short sEb[16][ROWE];   // 74.0 KB
    __shared__ float pD[16][776];                            // 49.7 KB
    __shared__ float sMp[16];
    __shared__ float sT[16][NNT];                            // 3 KB

    // ---- leaves for this b
    for (int e = tid; e < LL*NNT; e += 1024) {
        int i = e / NNT, n = e % NNT;
        int tok = tokens[b*LL + i];
        chart[ch_idx(b, i, i+1, n)] = __logf(fmaxf(lexical[(size_t)n*(size_t)T + (size_t)tok], EPSV));
    }

    const bf16x8* wp8 = (const bf16x8*)Wp;
    const int kstart = (w < 8) ? 5*w : 40 + 4*(w - 8);
    const int kcnt   = (w < 8) ? 5 : 4;
    const int m = lane & 15, kg = lane >> 4;

    // invariant kstep-0 B fragments (held in VGPR for the whole kernel)
    bf16x8 nb0 = wp8[(0*KSTEPS + kstart)*64 + lane];
    bf16x8 nb1 = wp8[(1*KSTEPS + kstart)*64 + lane];
    bf16x8 nb2 = wp8[(2*KSTEPS + kstart)*64 + lane];

    __syncthreads();   // leaves visible block-wide

    for (int s = 2; s <= LL; ++s) {
        const int pos = LL + 1 - s, nk = s - 1;
        int IPB = 1, ish = 0;
        while (IPB < pos && IPB < 16) { IPB <<= 1; ++ish; }
        const int wsh = 4 - ish;            // log2(WPI)
        const int WPI = 16 >> ish;
        const int q = w >> wsh, r = w & (WPI - 1);
        const int P = (pos + IPB - 1) >> ish;

        for (int p = 0; p < P; ++p) {
            const int i = p*IPB + q;
            const bool valid = (i < pos);
            const int j = i + s;

            float E[48];
            #pragma unroll
            for (int t = 0; t < 48; ++t) E[t] = 0.f;
            float mrun = -INFINITY;

            if (valid) {
                int kk = r;
                float nu = -INFINITY, nv = -INFINITY;
                if (kk < nk && lane < NNT) {
                    int k = i + kk + 1;
                    nu = chart[ch_idx(b, i, k, lane)];
                    nv = chart[ch_idx(b, k, j, lane)];
                }
                for (; kk < nk; kk += WPI) {
                    float u = nu, v = nv;
                    int kk2 = kk + WPI;
                    nu = -INFINITY; nv = -INFINITY;
                    if (kk2 < nk && lane < NNT) {
                        int k2 = i + kk2 + 1;
                        nu = chart[ch_idx(b, i, k2, lane)];
                        nv = chart[ch_idx(b, k2, j, lane)];
                    }
                    float au = u, bv = v;
                    #pragma unroll
                    for (int o = 32; o; o >>= 1) {
                        au = fmaxf(au, __shfl_xor(au, o));
                        bv = fmaxf(bv, __shfl_xor(bv, o));
                    }
                    float mnew = fmaxf(mrun, au + bv);
                    if (mnew > mrun && mrun != -INFINITY) {
                        float rs = __expf(mrun - mnew);
                        #pragma unroll
                        for (int t = 0; t < 48; ++t) E[t] *= rs;
                    }
                    mrun = mnew;
                    float eu = (lane < NNT) ? __expf(u - au) : 0.f;          // arg <= 0
                    float ev = (lane < NNT) ? __expf(v + au - mrun) : 0.f;   // arg <= 0
                    #pragma unroll
                    for (int bb = 0; bb < 48; ++bb) {
                        float eub = __int_as_float(__builtin_amdgcn_readlane(__float_as_int(eu), bb));
                        E[bb] = fmaf(eub, ev, E[bb]);
                    }
                }
            }
            if (lane == 0) sMp[w] = mrun;
            __syncthreads();
            float M = -INFINITY;
            {
                int base = w & ~(WPI - 1);
                for (int t = 0; t < WPI; ++t) M = fmaxf(M, sMp[base + t]);
            }
            const float scl = (mrun > -INFINITY) ? __expf(mrun - M) : 0.f;

            // pack lane-contiguous E (e = lane*48 + bb) -> 6 x ds_write_b128
            if (lane < NNT) {
                unsigned short* dst = &sEb[w][lane*NNT];
                #pragma unroll
                for (int t = 0; t < 6; ++t) {
                    bf16x8 pk;
                    #pragma unroll
                    for (int u2 = 0; u2 < 8; ++u2) pk[u2] = (short)f2bf(E[t*8 + u2] * scl);
                    *(bf16x8*)(dst + t*8) = pk;
                }
            }

            // prefetch remaining B fragments (uniform addresses; latency hides under barrier)
            bf16x8 tb[4][3];
            #pragma unroll
            for (int t = 0; t < 4; ++t) {
                if (t < kcnt - 1) {
                    tb[t][0] = wp8[(0*KSTEPS + kstart + 1 + t)*64 + lane];
                    tb[t][1] = wp8[(1*KSTEPS + kstart + 1 + t)*64 + lane];
                    tb[t][2] = wp8[(2*KSTEPS + kstart + 1 + t)*64 + lane];
                }
            }
            __syncthreads();

            // K-split MFMA GEMM [16 x 2304] x [2304 x 48]
            f32x4 a0 = {0.f,0.f,0.f,0.f}, a1 = {0.f,0.f,0.f,0.f}, a2 = {0.f,0.f,0.f,0.f};
            {
                bf16x8 af = *(const bf16x8*)&sEb[m][kstart*32 + (kg << 3)];
                a0 = __builtin_amdgcn_mfma_f32_16x16x32_bf16(af, nb0, a0, 0, 0, 0);
                a1 = __builtin_amdgcn_mfma_f32_16x16x32_bf16(af, nb1, a1, 0, 0, 0);
                a2 = __builtin_amdgcn_mfma_f32_16x16x32_bf16(af, nb2, a2, 0, 0, 0);
            }
            #pragma unroll
            for (int t = 0; t < 4; ++t) {
                if (t < kcnt - 1) {
                    bf16x8 af = *(const bf16x8*)&sEb[m][(kstart + 1 + t)*32 + (kg << 3)];
                    a0 = __builtin_amdgcn_mfma_f32_16x16x32_bf16(af, tb[t][0], a0, 0, 0, 0);
                    a1 = __builtin_amdgcn_mfma_f32_16x16x32_bf16(af, tb[t][1], a1, 0, 0, 0);
                    a2 = __builtin_amdgcn_mfma_f32_16x16x32_bf16(af, tb[t][2], a2, 0, 0, 0);
                }
            }
            #pragma unroll
            for (int rr = 0; rr < 4; ++rr) {
                int row = (lane >> 4)*4 + rr, col = lane & 15;
                pD[w][0*256 + row*16 + col] = a0[rr];
                pD[w][1*256 + row*16 + col] = a1[rr];
                pD[w][2*256 + row*16 + col] = a2[rr];
            }
            __syncthreads();

            // reduce 16 wave-partials
            if (tid < 768) {
                int m2 = tid / 48, n = tid % 48, nt = n >> 4, c = n & 15;
                float sm = 0.f;
                #pragma unroll
                for (int w2 = 0; w2 < 16; ++w2) sm += pD[w2][nt*256 + m2*16 + c];
                sT[m2][n] = sm;
            }
            __syncthreads();

            // combine WPI rows per instance, epilogue
            if (tid < IPB*48) {
                int q2 = tid / 48, n = tid % 48;
                int i2 = p*IPB + q2;
                if (i2 < pos) {
                    float sum = 0.f, Mq = -INFINITY;
                    int base = q2 << wsh;
                    for (int t = 0; t < WPI; ++t) {
                        sum += sT[base + t][n];
                        Mq = fmaxf(Mq, sMp[base + t]);
                    }
                    float val = Mq + logf(sum);
                    chart[ch_idx(b, i2, i2 + s, n)] = val;
                    if (s == LL && n == 0) out[b] = val;   // i2==0 forced (pos==1)
                }
            }
            __syncthreads();
        }
    }
}

extern "C" void kernel_launch(void* const* d_in, const int* in_sizes, int n_in,
                              void* d_out, int out_size, void* d_ws, size_t ws_size,
                              hipStream_t stream) {
    const int*   tokens  = (const int*)d_in[0];
    const float* binary  = (const float*)d_in[1];
    const float* lexical = (const float*)d_in[2];
    float* out = (float*)d_out;

    float* chart = (float*)d_ws;                                   // 6.49 MB
    unsigned short* Wp = (unsigned short*)(chart + (size_t)BB*LL*(LL+1)*NNT);  // 221 KB bf16

    int T = in_sizes[2] / NNT;   // 32000

    wpack_kernel<<<(3*KSTEPS*64*8 + 255)/256, 256, 0, stream>>>(binary, Wp);
    inside_kernel<<<BB, 1024, 0, stream>>>(Wp, tokens, lexical, chart, out, T);
}

// Round 7
// 454.828 us; speedup vs baseline: 1.8095x; 1.8095x over previous
//
#include <hip/hip_runtime.h>
#include <math.h>

#define NNT 48
#define LL 32
#define BB 32
#define N2 2304            // 48*48
#define KSTEPS 72          // 2304/32
#define EPSV 1e-30f
#define CH_J ((LL+1)*NNT)  // 1584: chart stride of the row index
#define SEB_S 2328         // shorts per sEb row (2304 + pad; 4656B -> rows 12 banks apart)
#define PD_NT 264          // floats per nt-tile in pD (256 + pad)
#define PD_S  (3*PD_NT)    // 792

typedef __attribute__((ext_vector_type(8))) short bf16x8;
typedef __attribute__((ext_vector_type(4))) float f32x4;

__device__ __forceinline__ int ch_idx(int b, int i, int j, int n) {
    return (((b*LL + i)*(LL+1) + j)*NNT + n);
}

__device__ __forceinline__ unsigned short f2bf(float x) {
    unsigned u = __float_as_uint(x);
    u = (u + 0x7fffu + ((u >> 16) & 1u)) >> 16;   // RNE
    return (unsigned short)u;
}

// EU/EV slab addressing (shorts): [q][r=0..47][k=0..31] bf16, 16B-chunk XOR
// swizzle (chunk ^= r&7; bijective) -> frag reads ~2-way, writes spread.
__device__ __forceinline__ int uvt_base(int q, int r, int kc) {
    return q*1536 + ((((r << 2) + kc) ^ (r & 7)) << 3);
}

__device__ __forceinline__ float wavemax(float x) {
    #pragma unroll
    for (int o = 32; o; o >>= 1) x = fmaxf(x, __shfl_xor(x, o));
    return x;
}

// Pack W[a][e] (e = c*48 + b') = clip(binary[a][b'][c]) into MFMA B-frag order:
// idx = ((nt*KSTEPS+ks)*64 + l)*8 + j ; e = ks*32 + (l>>4)*8 + j ; n = nt*16 + (l&15)
__global__ void wpack_kernel(const float* __restrict__ binary, unsigned short* __restrict__ Wp) {
    int idx = blockIdx.x*256 + threadIdx.x;
    if (idx >= 3*KSTEPS*64*8) return;
    int j  = idx & 7;
    int l  = (idx >> 3) & 63;
    int ks = (idx >> 9) % KSTEPS;
    int nt = idx / (KSTEPS*512);
    int e = ks*32 + ((l >> 4) << 3) + j;
    int n = nt*16 + (l & 15);
    int bp = e % 48, c = e / 48;
    float v = fmaxf(binary[n*N2 + bp*48 + c], EPSV);
    Wp[idx] = f2bf(v);
}

// One persistent block (512 thr, 8 waves) per batch element b; 31 levels serial.
// Per pass: IPB instances, WPI = 8/IPB waves each (split-parallel tail).
// Stage-1 per wave: per-split two-sided shift via cached row maxima cmax[i][j]
// (eu=exp(u-alpha_k)<=1, ev=exp(v+alpha_k-mw)<=1), bf16 slabs, 9 MFMA -> partial E.
// B1. Pack E*exp(mw-M) -> sEb row w. B2. Stage-2 K-split MFMA GEMM
// [16x2304]x[2304x48] -> pD. B3. Epilogue: sum partials, val = M + log(S),
// wave-butterfly row max -> cmax, write chart. B4.
__global__ __launch_bounds__(512, 2) void inside_kernel(
        const unsigned short* __restrict__ Wp,
        const int* __restrict__ tokens,
        const float* __restrict__ lexical,
        float* __restrict__ chart,
        float* __restrict__ out, int T) {
    const int b = blockIdx.x;
    const int tid = threadIdx.x, lane = tid & 63, w = tid >> 6;   // w 0..7
    const int fr = lane & 15, kg = lane >> 4;

    __shared__ __align__(16) short sUV[24576];      // EU | EV(+12288)   48.0 KB
    __shared__ __align__(16) short sEb[8*SEB_S];    // GEMM rows        37.2 KB
    __shared__ float pD[8*PD_S];                    //                  25.3 KB
    __shared__ float cmax[LL*33 + 33];              // row maxima        4.3 KB
    __shared__ float sM[8];

    // zero slabs once (finite-guarantee: B-frags are never masked; 0*NaN=NaN)
    for (int x = tid; x < 12288; x += 512) ((int*)sUV)[x] = 0;

    // leaves + leaf row maxima
    for (int row = w; row < LL; row += 8) {
        int tok = tokens[b*LL + row];
        float val = (lane < NNT)
            ? __logf(fmaxf(lexical[(size_t)lane*(size_t)T + (size_t)tok], EPSV))
            : -INFINITY;
        float rm = wavemax(val);
        if (lane < NNT) chart[ch_idx(b, row, row+1, lane)] = val;
        if (lane == 0) cmax[row*33 + row + 1] = rm;
    }
    __syncthreads();

    const bf16x8* wp8 = (const bf16x8*)Wp;
    const int kstart = 9*w;   // stage-2 K slice

    for (int s = 2; s <= LL; ++s) {
        const int pos = LL + 1 - s, nk = s - 1;
        int IPB = 1, ish = 0;
        while (IPB < pos && IPB < 8) { IPB <<= 1; ++ish; }
        const int wsh = 3 - ish;            // log2(WPI)
        const int WPI = 8 >> ish;
        const int q = w >> wsh, r = w & (WPI - 1);
        const int P = (pos + IPB - 1) >> ish;

        for (int p = 0; p < P; ++p) {
            const int i = p*IPB + q;
            const bool valid = (i < pos);
            const int j = i + s;
            const int tcnt = (valid && r < nk) ? ((nk - 1 - r)/WPI + 1) : 0;

            float mw = -INFINITY;
            f32x4 e00={0.f,0.f,0.f,0.f}, e01=e00, e02=e00,
                  e10=e00, e11=e00, e12=e00, e20=e00, e21=e00, e22=e00;

            if (tcnt > 0) {
                // sub-pass A: wave-partial max over owned splits (broadcast LDS reads)
                for (int t = 0; t < tcnt; ++t) {
                    int kk = r + t*WPI;
                    mw = fmaxf(mw, cmax[i*33 + i + 1 + kk] + cmax[(i+1+kk)*33 + j]);
                }
                // sub-pass B: exp + slab writes, batches of 4 slots (b64 writes)
                const float* up = chart + ch_idx(b, i, i+1, 0);
                const float* vp = chart + ch_idx(b, i+1, j, 0);
                const int ln = (lane < NNT) ? lane : 0;
                for (int t0 = 0; t0 < tcnt; t0 += 4) {
                    unsigned long long pu = 0ull, pv = 0ull;
                    #pragma unroll
                    for (int dt = 0; dt < 4; ++dt) {
                        int t = t0 + dt;
                        int tt = (t < tcnt) ? t : (tcnt - 1);   // clamp to OWNED split
                        int kk = r + tt*WPI;                    //  -> args stay <= 0
                        float al = cmax[i*33 + i + 1 + kk];
                        float u  = up[kk*NNT + ln];
                        float v  = vp[kk*CH_J + ln];
                        unsigned long long eu = f2bf(__expf(u - al));
                        unsigned long long ev = f2bf(__expf(v + al - mw));
                        pu |= eu << (16*dt);
                        pv |= ev << (16*dt);
                    }
                    if (lane < NNT) {
                        int ad = uvt_base(w, lane, t0 >> 3) + (t0 & 7);
                        *(unsigned long long*)&sUV[ad]         = pu;
                        *(unsigned long long*)&sUV[12288 + ad] = pv;
                    }
                }
                // stage-1 MFMA: partial E[b'][c] = sum_t EU[t][b'] * EV[t][c]
                bf16x8 A0 = *(const bf16x8*)&sUV[uvt_base(w, 0*16 + fr, kg)];
                bf16x8 A1 = *(const bf16x8*)&sUV[uvt_base(w, 1*16 + fr, kg)];
                bf16x8 A2 = *(const bf16x8*)&sUV[uvt_base(w, 2*16 + fr, kg)];
                #pragma unroll
                for (int jj = 0; jj < 8; ++jj) {
                    bool dead = (kg*8 + jj >= tcnt);
                    if (dead) { A0[jj] = 0; A1[jj] = 0; A2[jj] = 0; }
                }
                bf16x8 B0 = *(const bf16x8*)&sUV[12288 + uvt_base(w, 0*16 + fr, kg)];
                bf16x8 B1 = *(const bf16x8*)&sUV[12288 + uvt_base(w, 1*16 + fr, kg)];
                bf16x8 B2 = *(const bf16x8*)&sUV[12288 + uvt_base(w, 2*16 + fr, kg)];
                e00 = __builtin_amdgcn_mfma_f32_16x16x32_bf16(A0, B0, e00, 0,0,0);
                e01 = __builtin_amdgcn_mfma_f32_16x16x32_bf16(A0, B1, e01, 0,0,0);
                e02 = __builtin_amdgcn_mfma_f32_16x16x32_bf16(A0, B2, e02, 0,0,0);
                e10 = __builtin_amdgcn_mfma_f32_16x16x32_bf16(A1, B0, e10, 0,0,0);
                e11 = __builtin_amdgcn_mfma_f32_16x16x32_bf16(A1, B1, e11, 0,0,0);
                e12 = __builtin_amdgcn_mfma_f32_16x16x32_bf16(A1, B2, e12, 0,0,0);
                e20 = __builtin_amdgcn_mfma_f32_16x16x32_bf16(A2, B0, e20, 0,0,0);
                e21 = __builtin_amdgcn_mfma_f32_16x16x32_bf16(A2, B1, e21, 0,0,0);
                e22 = __builtin_amdgcn_mfma_f32_16x16x32_bf16(A2, B2, e22, 0,0,0);
            }
            if (lane == 0) sM[w] = mw;
            __syncthreads();   // B1

            // pack partial E * exp(mw - M) -> sEb row w (always: clears stale rows)
            {
                int base = w & ~(WPI - 1);
                float M = sM[base];
                #pragma unroll
                for (int t = 1; t < 8; ++t) if (t < WPI) M = fmaxf(M, sM[base + t]);
                float scl = (mw > -INFINITY) ? __expf(mw - M) : 0.f;
                #define PACKT(D, MT, CT)                                                   \
                    {                                                                      \
                        int e0 = ((CT)*16 + fr)*48 + (MT)*16 + kg*4;                       \
                        unsigned long long lo = (unsigned long long)f2bf(D[0]*scl)         \
                                              | ((unsigned long long)f2bf(D[1]*scl)<<16);  \
                        unsigned long long hi = (unsigned long long)f2bf(D[2]*scl)         \
                                              | ((unsigned long long)f2bf(D[3]*scl)<<16);  \
                        *(unsigned long long*)&sEb[w*SEB_S + e0] = lo | (hi << 32);        \
                    }
                PACKT(e00,0,0) PACKT(e01,0,1) PACKT(e02,0,2)
                PACKT(e10,1,0) PACKT(e11,1,1) PACKT(e12,1,2)
                PACKT(e20,2,0) PACKT(e21,2,1) PACKT(e22,2,2)
                #undef PACKT
            }
            __syncthreads();   // B2

            // stage-2: K-split MFMA GEMM (9 ksteps/wave), rows = wave partials
            {
                f32x4 c0 = {0.f,0.f,0.f,0.f}, c1 = c0, c2 = c0;
                const int mrow = fr & 7;   // 8 real rows, dup into 16-row M tile
                #pragma unroll
                for (int t = 0; t < 9; ++t) {
                    int ks = kstart + t;
                    bf16x8 af  = *(const bf16x8*)&sEb[mrow*SEB_S + ks*32 + kg*8];
                    bf16x8 wb0 = wp8[(0*KSTEPS + ks)*64 + lane];
                    bf16x8 wb1 = wp8[(1*KSTEPS + ks)*64 + lane];
                    bf16x8 wb2 = wp8[(2*KSTEPS + ks)*64 + lane];
                    c0 = __builtin_amdgcn_mfma_f32_16x16x32_bf16(af, wb0, c0, 0,0,0);
                    c1 = __builtin_amdgcn_mfma_f32_16x16x32_bf16(af, wb1, c1, 0,0,0);
                    c2 = __builtin_amdgcn_mfma_f32_16x16x32_bf16(af, wb2, c2, 0,0,0);
                }
                #pragma unroll
                for (int rr = 0; rr < 4; ++rr) {
                    int row = kg*4 + rr;
                    pD[w*PD_S + 0*PD_NT + row*16 + fr] = c0[rr];
                    pD[w*PD_S + 1*PD_NT + row*16 + fr] = c1[rr];
                    pD[w*PD_S + 2*PD_NT + row*16 + fr] = c2[rr];
                }
            }
            __syncthreads();   // B3

            // epilogue: wave w = instance w of this pass
            if (w < IPB) {
                int i2 = p*IPB + w;
                bool act = (i2 < pos);
                float val = -INFINITY;
                if (act) {
                    int base = w << wsh;
                    float Mq = sM[base];
                    #pragma unroll
                    for (int t = 1; t < 8; ++t) if (t < WPI) Mq = fmaxf(Mq, sM[base + t]);
                    int nn = (lane < NNT) ? lane : 0;
                    float sum = 0.f;
                    for (int w2 = 0; w2 < 8; ++w2) {
                        const float* pp = &pD[w2*PD_S + (nn >> 4)*PD_NT + (nn & 15)];
                        #pragma unroll
                        for (int t = 0; t < 8; ++t)
                            if (t < WPI) sum += pp[(base + t)*16];
                    }
                    val = Mq + __logf(sum);
                }
                float rm = wavemax((lane < NNT) ? val : -INFINITY);
                if (act) {
                    if (lane < NNT) chart[ch_idx(b, i2, i2 + s, lane)] = val;
                    if (lane == 0) {
                        cmax[i2*33 + i2 + s] = rm;
                        if (s == LL) out[b] = val;
                    }
                }
            }
            __syncthreads();   // B4
        }
    }
}

extern "C" void kernel_launch(void* const* d_in, const int* in_sizes, int n_in,
                              void* d_out, int out_size, void* d_ws, size_t ws_size,
                              hipStream_t stream) {
    const int*   tokens  = (const int*)d_in[0];
    const float* binary  = (const float*)d_in[1];
    const float* lexical = (const float*)d_in[2];
    float* out = (float*)d_out;

    float* chart = (float*)d_ws;                                   // 6.49 MB
    unsigned short* Wp = (unsigned short*)(chart + (size_t)BB*LL*(LL+1)*NNT);  // 221 KB bf16

    int T = in_sizes[2] / NNT;   // 32000

    wpack_kernel<<<(3*KSTEPS*64*8 + 255)/256, 256, 0, stream>>>(binary, Wp);
    inside_kernel<<<BB, 512, 0, stream>>>(Wp, tokens, lexical, chart, out, T);
}